// Round 1
// baseline (1478.962 us; speedup 1.0000x reference)
//
#include <hip/hip_runtime.h>

#define B_ 2
#define N_ 2048
#define DIM_ 640
#define NH_ 10
#define DH_ 64
#define DINNER_ 2560
#define L_ 4
#define FDIM_ 280
#define FDIMP_ 288
#define FEATD_ 576
#define NFEAT_ 19
#define ROWS_ (B_*N_)   /* 4096 */

typedef __attribute__((ext_vector_type(8))) unsigned short ushort8;
typedef __attribute__((ext_vector_type(8))) __bf16 bf16x8;
typedef __attribute__((ext_vector_type(4))) float f32x4;

static __device__ __forceinline__ unsigned short f2bf(float f){
  unsigned int u = __builtin_bit_cast(unsigned int, f);
  u += 0x7fffu + ((u >> 16) & 1u);
  return (unsigned short)(u >> 16);
}

static __device__ __forceinline__ f32x4 mfma16(ushort8 a, ushort8 b, f32x4 c){
  return __builtin_amdgcn_mfma_f32_16x16x32_bf16(
      __builtin_bit_cast(bf16x8, a), __builtin_bit_cast(bf16x8, b), c, 0, 0, 0);
}

// ---------------- weight conversion ----------------
__global__ __launch_bounds__(256) void conv_kernel(const float* __restrict__ src,
    unsigned short* __restrict__ dst, int n){
  int i = blockIdx.x*256 + threadIdx.x;
  int stride = gridDim.x*256;
  for (; i<n; i+=stride) dst[i] = f2bf(src[i]);
}

__global__ __launch_bounds__(256) void convpad_kernel(const float* __restrict__ src,
    unsigned short* __restrict__ dst, int rows, int cols, int ld){
  int n = rows*ld;
  int i = blockIdx.x*256 + threadIdx.x;
  int stride = gridDim.x*256;
  for (; i<n; i+=stride){
    int r = i/ld, c = i%ld;
    dst[i] = (c<cols) ? f2bf(src[r*cols+c]) : (unsigned short)0;
  }
}

// ---------------- embedding ----------------
__global__ __launch_bounds__(256) void embed_kernel(const float* __restrict__ xf,
    const int* __restrict__ xt, const float* __restrict__ e0, const float* __restrict__ e1,
    const float* __restrict__ fw, const float* __restrict__ fb, float* __restrict__ Z){
  int row = blockIdx.x;
  __shared__ float f[NFEAT_];
  int t = threadIdx.x;
  if (t < NFEAT_) f[t] = xf[row*NFEAT_ + t];
  __syncthreads();
  if (t < 32) {
    int tok0 = xt[row*2];
    Z[(size_t)row*DIM_ + t] = e0[tok0*32 + t];
  } else if (t < 64) {
    int tok1 = xt[row*2+1];
    Z[(size_t)row*DIM_ + t] = e1[tok1*32 + (t-32)];
  }
  for (int fo = t; fo < FEATD_; fo += 256){
    float acc = fb[fo];
    #pragma unroll
    for (int k=0;k<NFEAT_;k++) acc += f[k]*fw[fo*NFEAT_+k];
    Z[(size_t)row*DIM_ + 64 + fo] = acc;
  }
}

// ---------------- layernorm (fp32 in -> bf16 out) ----------------
__global__ __launch_bounds__(256) void ln_kernel(const float* __restrict__ X,
    const float* __restrict__ g, const float* __restrict__ bb,
    unsigned short* __restrict__ out){
  int lane = threadIdx.x & 63;
  int row = blockIdx.x*4 + (threadIdx.x >> 6);
  const float* x = X + (size_t)row*DIM_;
  float v[10]; float s=0.f, sq=0.f;
  #pragma unroll
  for (int j=0;j<10;j++){ float t = x[lane + j*64]; v[j]=t; s+=t; sq+=t*t; }
  #pragma unroll
  for (int off=1; off<64; off<<=1){ s += __shfl_xor(s, off, 64); sq += __shfl_xor(sq, off, 64); }
  float mean = s*(1.f/DIM_);
  float var = sq*(1.f/DIM_) - mean*mean;
  float rstd = rsqrtf(var + 1e-5f);
  unsigned short* o = out + (size_t)row*DIM_;
  #pragma unroll
  for (int j=0;j<10;j++){ int c = lane + j*64; o[c] = f2bf((v[j]-mean)*rstd*g[c] + bb[c]); }
}

// ---------------- GEMM: C = A(MxK) * Bw(NxK)^T, 128x128 tile ----------------
template<bool BIAS, bool RELU, bool RES, bool OUTF, bool OUTB>
__global__ __launch_bounds__(256) void gemm_kernel(
    const unsigned short* __restrict__ A, int lda,
    const unsigned short* __restrict__ Bw, int ldb,
    const float* __restrict__ bias,
    const float* __restrict__ Res, int ldres,
    float* __restrict__ Cf, int ldcf,
    unsigned short* __restrict__ Cb, int ldcb,
    int Ncols, int K)
{
  __shared__ __align__(16) unsigned short As[128*32];
  __shared__ __align__(16) unsigned short Bs[128*32];
  int t = threadIdx.x;
  int wid = t >> 6, lane = t & 63;
  int wr = wid >> 1, wc = wid & 1;
  int lg = lane >> 4, lm = lane & 15;
  int row0 = blockIdx.y * 128;
  int col0 = blockIdx.x * 128;

  f32x4 acc[4][4];
  #pragma unroll
  for (int m=0;m<4;m++)
    #pragma unroll
    for (int n=0;n<4;n++) acc[m][n] = f32x4{0.f,0.f,0.f,0.f};

  for (int kt=0; kt<K; kt+=32){
    #pragma unroll
    for (int j=0;j<2;j++){
      int c = wid*128 + j*64 + lane;
      int ar = c >> 2, aq = c & 3;
      const unsigned short* sa = A + (size_t)(row0+ar)*lda + kt + aq*8;
      __builtin_amdgcn_global_load_lds(
          (const __attribute__((address_space(1))) void*)sa,
          (__attribute__((address_space(3))) void*)(As + c*8), 16, 0, 0);
      int br = col0 + ar; if (br >= Ncols) br = Ncols-1;
      const unsigned short* sb = Bw + (size_t)br*ldb + kt + aq*8;
      __builtin_amdgcn_global_load_lds(
          (const __attribute__((address_space(1))) void*)sb,
          (__attribute__((address_space(3))) void*)(Bs + c*8), 16, 0, 0);
    }
    __syncthreads();
    ushort8 af[4], bfr[4];
    #pragma unroll
    for (int m=0;m<4;m++) af[m] = *(const ushort8*)(As + (wr*64 + m*16 + lm)*32 + lg*8);
    #pragma unroll
    for (int n=0;n<4;n++) bfr[n] = *(const ushort8*)(Bs + (wc*64 + n*16 + lm)*32 + lg*8);
    #pragma unroll
    for (int m=0;m<4;m++)
      #pragma unroll
      for (int n=0;n<4;n++)
        acc[m][n] = mfma16(af[m], bfr[n], acc[m][n]);
    __syncthreads();
  }

  #pragma unroll
  for (int m=0;m<4;m++){
    int rbase = row0 + wr*64 + m*16 + lg*4;
    #pragma unroll
    for (int n=0;n<4;n++){
      int cc = col0 + wc*64 + n*16 + lm;
      if (cc < Ncols){
        float bv = 0.f;
        if (BIAS) bv = bias[cc];
        #pragma unroll
        for (int rr=0;rr<4;rr++){
          float v = acc[m][n][rr] + bv;
          if (RELU) v = fmaxf(v, 0.f);
          if (RES) v += Res[(size_t)(rbase+rr)*ldres + cc];
          if (OUTF) Cf[(size_t)(rbase+rr)*ldcf + cc] = v;
          if (OUTB) Cb[(size_t)(rbase+rr)*ldcb + cc] = f2bf(v);
        }
      }
    }
  }
}

// ---------------- flash attention: qkv bf16 [row][h*192 + {V:0,Q:64,K:128}+d] ----------------
__global__ __launch_bounds__(256) void attn_kernel(const unsigned short* __restrict__ qkv,
    const float* __restrict__ mask, unsigned short* __restrict__ att){
  int bh = blockIdx.y;
  int b = bh / NH_, h = bh % NH_;
  int wid = threadIdx.x >> 6, lane = threadIdx.x & 63;
  int lg = lane >> 4, lm = lane & 15;
  int q0 = blockIdx.x*64 + wid*16;

  __shared__ __align__(16) unsigned short VT[64*40];
  __shared__ __align__(16) unsigned short P[4][16*40];

  const size_t base = (size_t)b*N_*1920 + (size_t)h*192;

  ushort8 qf[2];
  #pragma unroll
  for (int ss=0; ss<2; ss++)
    qf[ss] = *(const ushort8*)(qkv + base + (size_t)(q0+lm)*1920 + 64 + ss*32 + lg*8);

  float mq[4];
  #pragma unroll
  for (int r=0;r<4;r++) mq[r] = mask[b*N_ + q0 + lg*4 + r];

  float mrun[4], lsum[4];
  f32x4 o[4];
  #pragma unroll
  for (int r=0;r<4;r++){ mrun[r] = -1e30f; lsum[r]=0.f; o[r] = f32x4{0.f,0.f,0.f,0.f}; }

  for (int kt=0; kt<N_; kt+=32){
    { // stage V transposed: VT[d][kk], stride 40
      int kk = threadIdx.x >> 3;
      int j0 = (threadIdx.x & 7)*8;
      ushort8 vv = *(const ushort8*)(qkv + base + (size_t)(kt+kk)*1920 + j0);
      #pragma unroll
      for (int j=0;j<8;j++) VT[(j0+j)*40 + kk] = vv[j];
    }
    __syncthreads();

    f32x4 sf[2]; float mk[2];
    #pragma unroll
    for (int c=0;c<2;c++){
      mk[c] = mask[b*N_ + kt + c*16 + lm];
      f32x4 s = f32x4{0.f,0.f,0.f,0.f};
      #pragma unroll
      for (int ss=0;ss<2;ss++){
        ushort8 kf = *(const ushort8*)(qkv + base + (size_t)(kt + c*16 + lm)*1920 + 128 + ss*32 + lg*8);
        s = mfma16(qf[ss], kf, s);
      }
      #pragma unroll
      for (int r=0;r<4;r++){
        float sv = s[r]*0.125f;
        sf[c][r] = (mq[r]*mk[c] > 0.f) ? sv : -1e20f;
      }
    }
    // online softmax (rows live across lanes 0..15 of each 16-lane group)
    float pm[2][4];
    #pragma unroll
    for (int r=0;r<4;r++){
      float tm = fmaxf(sf[0][r], sf[1][r]);
      #pragma unroll
      for (int x=1;x<16;x<<=1) tm = fmaxf(tm, __shfl_xor(tm, x, 64));
      float mnew = fmaxf(mrun[r], tm);
      float scale = __expf(mrun[r]-mnew);
      float p0 = __expf(sf[0][r]-mnew);
      float p1 = __expf(sf[1][r]-mnew);
      float rs = p0+p1;
      #pragma unroll
      for (int x=1;x<16;x<<=1) rs += __shfl_xor(rs, x, 64);
      lsum[r] = lsum[r]*scale + rs;
      mrun[r] = mnew;
      #pragma unroll
      for (int dn=0;dn<4;dn++) o[dn][r] *= scale;
      pm[0][r] = p0*mq[r]*mk[0];
      pm[1][r] = p1*mq[r]*mk[1];
    }
    // store P (with mask2 folded in), wave-private region
    #pragma unroll
    for (int c=0;c<2;c++)
      #pragma unroll
      for (int r=0;r<4;r++)
        P[wid][(lg*4+r)*40 + c*16 + lm] = f2bf(pm[c][r]);
    // PV
    ushort8 pa = *(const ushort8*)(&P[wid][lm*40 + lg*8]);
    #pragma unroll
    for (int dn=0;dn<4;dn++){
      ushort8 vb = *(const ushort8*)(&VT[(dn*16+lm)*40 + lg*8]);
      o[dn] = mfma16(pa, vb, o[dn]);
    }
    __syncthreads();
  }

  #pragma unroll
  for (int dn=0;dn<4;dn++)
    #pragma unroll
    for (int r=0;r<4;r++){
      int q = q0 + lg*4 + r;
      float v = o[dn][r] / lsum[r];
      v = (v >= 0.f) ? v : 0.01f*v;   // leaky_relu fused
      att[(size_t)(b*N_+q)*DIM_ + h*64 + dn*16 + lm] = f2bf(v);
    }
}

// ---------------- final output dot ----------------
__global__ __launch_bounds__(256) void out_kernel(const float* __restrict__ hf,
    const float* __restrict__ ow, const float* __restrict__ ob, float* __restrict__ out){
  int lane = threadIdx.x & 63;
  int row = blockIdx.x*4 + (threadIdx.x>>6);
  const float* x = hf + (size_t)row*FDIM_;
  float s = 0.f;
  for (int j=lane;j<FDIM_;j+=64) s += x[j]*ow[j];
  #pragma unroll
  for (int off=1; off<64; off<<=1) s += __shfl_xor(s, off, 64);
  if (lane==0) out[row] = s + ob[0];
}

extern "C" void kernel_launch(void* const* d_in, const int* in_sizes, int n_in,
                              void* d_out, int out_size, void* d_ws, size_t ws_size,
                              hipStream_t stream)
{
  const float* x_feats = (const float*)d_in[0];
  const int*   x_toks  = (const int*)d_in[1];
  const float* mask    = (const float*)d_in[2];
  const float* emb0    = (const float*)d_in[3];
  const float* emb1    = (const float*)d_in[4];
  const float* feat_w  = (const float*)d_in[5];
  const float* feat_b  = (const float*)d_in[6];
  const float* qkv_w   = (const float*)d_in[7];
  const float* qkv_b   = (const float*)d_in[8];
  const float* o_w     = (const float*)d_in[9];
  const float* ln1_g   = (const float*)d_in[10];
  const float* ln1_b   = (const float*)d_in[11];
  const float* ln2_g   = (const float*)d_in[12];
  const float* ln2_b   = (const float*)d_in[13];
  const float* p1_w    = (const float*)d_in[14];
  const float* p1_b    = (const float*)d_in[15];
  const float* p2_w    = (const float*)d_in[16];
  const float* p2_b    = (const float*)d_in[17];
  const float* fn_g    = (const float*)d_in[18];
  const float* fn_b    = (const float*)d_in[19];
  const float* lin1_w  = (const float*)d_in[20];
  const float* lin1_b  = (const float*)d_in[21];
  const float* rb1_w   = (const float*)d_in[22];
  const float* rb1_b   = (const float*)d_in[23];
  const float* rb2_w   = (const float*)d_in[24];
  const float* rb2_b   = (const float*)d_in[25];
  const float* out_w   = (const float*)d_in[26];
  const float* out_b   = (const float*)d_in[27];
  float* out = (float*)d_out;

  char* w = (char*)d_ws;
  auto alloc = [&](size_t bytes)->void*{ void* p = (void*)w; w += (bytes + 255) & ~(size_t)255; return p; };

  float* Z              = (float*)alloc((size_t)ROWS_*DIM_*4);
  unsigned short* Zn    = (unsigned short*)alloc((size_t)ROWS_*DIM_*2);
  unsigned short* qkvB  = (unsigned short*)alloc((size_t)ROWS_*1920*2);
  unsigned short* attB  = (unsigned short*)alloc((size_t)ROWS_*DIM_*2);
  unsigned short* Hb    = (unsigned short*)alloc((size_t)ROWS_*DINNER_*2);
  float* hf             = (float*)alloc((size_t)ROWS_*FDIM_*4);
  unsigned short* hb1   = (unsigned short*)alloc((size_t)ROWS_*FDIMP_*2);
  unsigned short* hb2   = (unsigned short*)alloc((size_t)ROWS_*FDIMP_*2);
  unsigned short* qkvw  = (unsigned short*)alloc((size_t)L_*1920*DIM_*2);
  unsigned short* oww   = (unsigned short*)alloc((size_t)L_*DIM_*DIM_*2);
  unsigned short* p1w   = (unsigned short*)alloc((size_t)L_*DINNER_*DIM_*2);
  unsigned short* p2w   = (unsigned short*)alloc((size_t)L_*DIM_*DINNER_*2);
  unsigned short* l1w   = (unsigned short*)alloc((size_t)FDIM_*DIM_*2);
  unsigned short* r1w   = (unsigned short*)alloc((size_t)FDIM_*FDIMP_*2);
  unsigned short* r2w   = (unsigned short*)alloc((size_t)FDIM_*FDIMP_*2);

  conv_kernel<<<2048,256,0,stream>>>(qkv_w, qkvw, L_*1920*DIM_);
  conv_kernel<<<1024,256,0,stream>>>(o_w,   oww,  L_*DIM_*DIM_);
  conv_kernel<<<2048,256,0,stream>>>(p1_w,  p1w,  L_*DINNER_*DIM_);
  conv_kernel<<<2048,256,0,stream>>>(p2_w,  p2w,  L_*DIM_*DINNER_);
  conv_kernel<<<256,256,0,stream>>>(lin1_w, l1w,  FDIM_*DIM_);
  convpad_kernel<<<128,256,0,stream>>>(rb1_w, r1w, FDIM_, FDIM_, FDIMP_);
  convpad_kernel<<<128,256,0,stream>>>(rb2_w, r2w, FDIM_, FDIM_, FDIMP_);
  hipMemsetAsync(hb1, 0, (size_t)ROWS_*FDIMP_*2, stream);
  hipMemsetAsync(hb2, 0, (size_t)ROWS_*FDIMP_*2, stream);

  embed_kernel<<<ROWS_,256,0,stream>>>(x_feats, x_toks, emb0, emb1, feat_w, feat_b, Z);

  for (int l=0; l<L_; l++){
    ln_kernel<<<ROWS_/4,256,0,stream>>>(Z, ln1_g + l*DIM_, ln1_b + l*DIM_, Zn);
    gemm_kernel<true,false,false,false,true><<<dim3(15,32),256,0,stream>>>(
        Zn, DIM_, qkvw + (size_t)l*1920*DIM_, DIM_, qkv_b + l*1920,
        nullptr, 0, nullptr, 0, qkvB, 1920, 1920, DIM_);
    attn_kernel<<<dim3(N_/64, B_*NH_),256,0,stream>>>(qkvB, mask, attB);
    gemm_kernel<false,false,true,true,false><<<dim3(5,32),256,0,stream>>>(
        attB, DIM_, oww + (size_t)l*DIM_*DIM_, DIM_, nullptr,
        Z, DIM_, Z, DIM_, nullptr, 0, DIM_, DIM_);
    ln_kernel<<<ROWS_/4,256,0,stream>>>(Z, ln2_g + l*DIM_, ln2_b + l*DIM_, Zn);
    gemm_kernel<true,true,false,false,true><<<dim3(20,32),256,0,stream>>>(
        Zn, DIM_, p1w + (size_t)l*DINNER_*DIM_, DIM_, p1_b + l*DINNER_,
        nullptr, 0, nullptr, 0, Hb, DINNER_, DINNER_, DIM_);
    gemm_kernel<true,false,true,true,false><<<dim3(5,32),256,0,stream>>>(
        Hb, DINNER_, p2w + (size_t)l*DIM_*DINNER_, DINNER_, p2_b + l*DIM_,
        Z, DIM_, Z, DIM_, nullptr, 0, DIM_, DINNER_);
  }

  ln_kernel<<<ROWS_/4,256,0,stream>>>(Z, fn_g, fn_b, Zn);
  gemm_kernel<true,false,false,true,true><<<dim3(3,32),256,0,stream>>>(
      Zn, DIM_, l1w, DIM_, lin1_b, nullptr, 0, hf, FDIM_, hb1, FDIMP_, FDIM_, DIM_);
  gemm_kernel<true,true,false,false,true><<<dim3(3,32),256,0,stream>>>(
      hb1, FDIMP_, r1w, FDIMP_, rb1_b, nullptr, 0, nullptr, 0, hb2, FDIMP_, FDIM_, FDIMP_);
  gemm_kernel<true,false,true,true,false><<<dim3(3,32),256,0,stream>>>(
      hb2, FDIMP_, r2w, FDIMP_, rb2_b, hf, FDIM_, hf, FDIM_, nullptr, 0, FDIM_, FDIMP_);
  out_kernel<<<ROWS_/4,256,0,stream>>>(hf, out_w, out_b, out);
}

// Round 3
// 932.787 us; speedup vs baseline: 1.5855x; 1.5855x over previous
//
#include <hip/hip_runtime.h>

#define B_ 2
#define N_ 2048
#define DIM_ 640
#define NH_ 10
#define DH_ 64
#define DINNER_ 2560
#define L_ 4
#define FDIM_ 280
#define FDIMP_ 288
#define FEATD_ 576
#define NFEAT_ 19
#define ROWS_ (B_*N_)   /* 4096 */

typedef __attribute__((ext_vector_type(8))) unsigned short ushort8;
typedef __attribute__((ext_vector_type(8))) __bf16 bf16x8;
typedef __attribute__((ext_vector_type(4))) float f32x4;
typedef __attribute__((ext_vector_type(2))) unsigned int u32x2;

static __device__ __forceinline__ unsigned short f2bf(float f){
  unsigned int u = __builtin_bit_cast(unsigned int, f);
  u += 0x7fffu + ((u >> 16) & 1u);
  return (unsigned short)(u >> 16);
}

static __device__ __forceinline__ f32x4 mfma16(ushort8 a, ushort8 b, f32x4 c){
  return __builtin_amdgcn_mfma_f32_16x16x32_bf16(
      __builtin_bit_cast(bf16x8, a), __builtin_bit_cast(bf16x8, b), c, 0, 0, 0);
}

static __device__ __forceinline__ ushort8 mk8(u32x2 lo, u32x2 hi){
  union { unsigned int u[4]; ushort8 s; } u_;
  u_.u[0]=lo[0]; u_.u[1]=lo[1]; u_.u[2]=hi[0]; u_.u[3]=hi[1];
  return u_.s;
}

#define GLD(src,dst) __builtin_amdgcn_global_load_lds((const __attribute__((address_space(1))) void*)(src), (__attribute__((address_space(3))) void*)(dst), 16, 0, 0)

// ---------------- weight conversion ----------------
__global__ __launch_bounds__(256) void conv_kernel(const float* __restrict__ src,
    unsigned short* __restrict__ dst, int n){
  int i = blockIdx.x*256 + threadIdx.x;
  int stride = gridDim.x*256;
  for (; i<n; i+=stride) dst[i] = f2bf(src[i]);
}

__global__ __launch_bounds__(256) void convpad_kernel(const float* __restrict__ src,
    unsigned short* __restrict__ dst, int rows, int cols, int ld){
  int n = rows*ld;
  int i = blockIdx.x*256 + threadIdx.x;
  int stride = gridDim.x*256;
  for (; i<n; i+=stride){
    int r = i/ld, c = i%ld;
    dst[i] = (c<cols) ? f2bf(src[r*cols+c]) : (unsigned short)0;
  }
}

// ---------------- embedding ----------------
__global__ __launch_bounds__(256) void embed_kernel(const float* __restrict__ xf,
    const int* __restrict__ xt, const float* __restrict__ e0, const float* __restrict__ e1,
    const float* __restrict__ fw, const float* __restrict__ fb, float* __restrict__ Z){
  int row = blockIdx.x;
  __shared__ float f[NFEAT_];
  int t = threadIdx.x;
  if (t < NFEAT_) f[t] = xf[row*NFEAT_ + t];
  __syncthreads();
  if (t < 32) {
    int tok0 = xt[row*2];
    Z[(size_t)row*DIM_ + t] = e0[tok0*32 + t];
  } else if (t < 64) {
    int tok1 = xt[row*2+1];
    Z[(size_t)row*DIM_ + t] = e1[tok1*32 + (t-32)];
  }
  for (int fo = t; fo < FEATD_; fo += 256){
    float acc = fb[fo];
    #pragma unroll
    for (int k=0;k<NFEAT_;k++) acc += f[k]*fw[fo*NFEAT_+k];
    Z[(size_t)row*DIM_ + 64 + fo] = acc;
  }
}

// ---------------- layernorm (fp32 in -> bf16 out) ----------------
__global__ __launch_bounds__(256) void ln_kernel(const float* __restrict__ X,
    const float* __restrict__ g, const float* __restrict__ bb,
    unsigned short* __restrict__ out){
  int lane = threadIdx.x & 63;
  int row = blockIdx.x*4 + (threadIdx.x >> 6);
  const float* x = X + (size_t)row*DIM_;
  float v[10]; float s=0.f, sq=0.f;
  #pragma unroll
  for (int j=0;j<10;j++){ float t = x[lane + j*64]; v[j]=t; s+=t; sq+=t*t; }
  #pragma unroll
  for (int off=1; off<64; off<<=1){ s += __shfl_xor(s, off, 64); sq += __shfl_xor(sq, off, 64); }
  float mean = s*(1.f/DIM_);
  float var = sq*(1.f/DIM_) - mean*mean;
  float rstd = rsqrtf(var + 1e-5f);
  unsigned short* o = out + (size_t)row*DIM_;
  #pragma unroll
  for (int j=0;j<10;j++){ int c = lane + j*64; o[c] = f2bf((v[j]-mean)*rstd*g[c] + bb[c]); }
}

// ---------------- GEMM: C = A(MxK) * Bw(NxK)^T, 128x128 tile ----------------
template<bool BIAS, bool RELU, bool RES, bool OUTF, bool OUTB>
__global__ __launch_bounds__(256) void gemm_kernel(
    const unsigned short* __restrict__ A, int lda,
    const unsigned short* __restrict__ Bw, int ldb,
    const float* __restrict__ bias,
    const float* __restrict__ Res, int ldres,
    float* __restrict__ Cf, int ldcf,
    unsigned short* __restrict__ Cb, int ldcb,
    int Ncols, int K)
{
  __shared__ __align__(16) unsigned short As[128*32];
  __shared__ __align__(16) unsigned short Bs[128*32];
  int t = threadIdx.x;
  int wid = t >> 6, lane = t & 63;
  int wr = wid >> 1, wc = wid & 1;
  int lg = lane >> 4, lm = lane & 15;
  int row0 = blockIdx.y * 128;
  int col0 = blockIdx.x * 128;

  f32x4 acc[4][4];
  #pragma unroll
  for (int m=0;m<4;m++)
    #pragma unroll
    for (int n=0;n<4;n++) acc[m][n] = f32x4{0.f,0.f,0.f,0.f};

  for (int kt=0; kt<K; kt+=32){
    #pragma unroll
    for (int j=0;j<2;j++){
      int c = wid*128 + j*64 + lane;
      int ar = c >> 2, aq = c & 3;
      const unsigned short* sa = A + (size_t)(row0+ar)*lda + kt + aq*8;
      GLD(sa, As + c*8);
      int br = col0 + ar; if (br >= Ncols) br = Ncols-1;
      const unsigned short* sb = Bw + (size_t)br*ldb + kt + aq*8;
      GLD(sb, Bs + c*8);
    }
    __syncthreads();
    ushort8 af[4], bfr[4];
    #pragma unroll
    for (int m=0;m<4;m++) af[m] = *(const ushort8*)(As + (wr*64 + m*16 + lm)*32 + lg*8);
    #pragma unroll
    for (int n=0;n<4;n++) bfr[n] = *(const ushort8*)(Bs + (wc*64 + n*16 + lm)*32 + lg*8);
    #pragma unroll
    for (int m=0;m<4;m++)
      #pragma unroll
      for (int n=0;n<4;n++)
        acc[m][n] = mfma16(af[m], bfr[n], acc[m][n]);
    __syncthreads();
  }

  #pragma unroll
  for (int m=0;m<4;m++){
    int rbase = row0 + wr*64 + m*16 + lg*4;
    #pragma unroll
    for (int n=0;n<4;n++){
      int cc = col0 + wc*64 + n*16 + lm;
      if (cc < Ncols){
        float bv = 0.f;
        if (BIAS) bv = bias[cc];
        #pragma unroll
        for (int rr=0;rr<4;rr++){
          float v = acc[m][n][rr] + bv;
          if (RELU) v = fmaxf(v, 0.f);
          if (RES) v += Res[(size_t)(rbase+rr)*ldres + cc];
          if (OUTF) Cf[(size_t)(rbase+rr)*ldcf + cc] = v;
          if (OUTB) Cb[(size_t)(rbase+rr)*ldcb + cc] = f2bf(v);
        }
      }
    }
  }
}

// ---------------- flash attention, KVBLK=64, double-buffered, swizzled K, subtiled V + tr reads
// qkv bf16 [row][h*192 + {V:0,Q:64,K:128}+d]
__global__ __launch_bounds__(256) void attn_kernel(const unsigned short* __restrict__ qkv,
    const float* __restrict__ mask, unsigned short* __restrict__ att){
  int bh = blockIdx.y; int b = bh/NH_, h = bh%NH_;
  int t = threadIdx.x; int wid = t>>6, lane = t&63, lg = lane>>4, lm = lane&15;
  int q0 = blockIdx.x*64 + wid*16;

  __shared__ __align__(128) unsigned short Ks[2][4096];
  __shared__ __align__(128) unsigned short Vs[2][4096];
  __shared__ __align__(16) unsigned short Pl[4][16*72];
  __shared__ __align__(16) float maskL[N_];

  const size_t base = (size_t)b*N_*1920 + (size_t)h*192;

  // per-thread staging constants (chunk = 16B)
  int c0 = t, c1 = t+256;
  int kk0 = c0>>3, kc0 = (c0&7)^(kk0&7);
  int kk1 = c1>>3, kc1 = (c1&7)^(kk1&7);
  const unsigned short* kS0 = qkv + base + 128 + (size_t)kk0*1920 + kc0*8;
  const unsigned short* kS1 = qkv + base + 128 + (size_t)kk1*1920 + kc1*8;
  // V subtiled [k>>2][d>>4][k&3][d&15]: chunk c -> k = ((c>>5)<<2)|((c>>1)&3), d8 = (((c>>3)&3)<<1)|(c&1)
  int vk0 = ((c0>>5)<<2)|((c0>>1)&3), vd0 = (((c0>>3)&3)<<1)|(c0&1);
  int vk1 = ((c1>>5)<<2)|((c1>>1)&3), vd1 = (((c1>>3)&3)<<1)|(c1&1);
  const unsigned short* vS0 = qkv + base + (size_t)vk0*1920 + vd0*8;
  const unsigned short* vS1 = qkv + base + (size_t)vk1*1920 + vd1*8;

  // Q fragments + query-row mask (issued before staging -> older in vmcnt order)
  ushort8 qf[2];
  #pragma unroll
  for (int ss=0; ss<2; ss++)
    qf[ss] = *(const ushort8*)(qkv + base + (size_t)(q0+lm)*1920 + 64 + ss*32 + lg*8);
  float mq[4];
  #pragma unroll
  for (int r=0;r<4;r++) mq[r] = mask[b*N_ + q0 + lg*4 + r];

  // prologue staging: mask row + tile 0
  GLD(mask + b*N_ + c0*4, &maskL[c0*4]);
  GLD(mask + b*N_ + c1*4, &maskL[c1*4]);
  GLD(kS0, &Ks[0][c0*8]); GLD(kS1, &Ks[0][c1*8]);
  GLD(vS0, &Vs[0][c0*8]); GLD(vS1, &Vs[0][c1*8]);

  float lp[4] = {0.f,0.f,0.f,0.f};
  f32x4 o[4];
  #pragma unroll
  for (int dn=0;dn<4;dn++) o[dn] = f32x4{0.f,0.f,0.f,0.f};

  for (int it=0; it<N_/64; ++it){
    int cur = it & 1;
    if (it < N_/64 - 1){
      const size_t adv = (size_t)(it+1)*64*1920;
      GLD(kS0+adv, &Ks[1-cur][c0*8]); GLD(kS1+adv, &Ks[1-cur][c1*8]);
      GLD(vS0+adv, &Vs[1-cur][c0*8]); GLD(vS1+adv, &Vs[1-cur][c1*8]);
      asm volatile("s_waitcnt vmcnt(4)" ::: "memory");
    } else {
      asm volatile("s_waitcnt vmcnt(0)" ::: "memory");
    }
    __builtin_amdgcn_s_barrier();
    asm volatile("" ::: "memory");

    // ---- QK^T (swizzled K reads) ----
    const unsigned short* Kc = &Ks[cur][0];
    f32x4 sf[4];
    float mk[4];
    #pragma unroll
    for (int c=0;c<4;c++){
      mk[c] = maskL[it*64 + c*16 + lm];
      int krow = c*16 + lm;
      f32x4 s = f32x4{0.f,0.f,0.f,0.f};
      #pragma unroll
      for (int ss=0;ss<2;ss++){
        ushort8 kf = *(const ushort8*)(Kc + (krow*8 + ((ss*4+lg)^(krow&7)))*8);
        s = mfma16(qf[ss], kf, s);
      }
      sf[c] = s;
    }

    // ---- fixed-max softmax numerators (scale-invariant; masked -> exact 0) ----
    float pm[4][4];
    #pragma unroll
    for (int c=0;c<4;c++){
      #pragma unroll
      for (int r=0;r<4;r++){
        float x = fmaf(sf[c][r], 0.125f, -12.0f);
        x = (mq[r]*mk[c] > 0.f) ? x : -1e30f;
        pm[c][r] = __expf(x);
      }
    }
    #pragma unroll
    for (int r=0;r<4;r++) lp[r] += (pm[0][r]+pm[1][r]) + (pm[2][r]+pm[3][r]);
    #pragma unroll
    for (int c=0;c<4;c++)
      #pragma unroll
      for (int r=0;r<4;r++)
        Pl[wid][(lg*4+r)*72 + c*16 + lm] = f2bf(pm[c][r]);

    // ---- P·V via hardware transpose reads on subtiled V ----
    // tr_b16 semantics: elem j = tile128B(addr & ~127)[row j][col (addr&127)>>3]
    unsigned vsb = (unsigned)(size_t)(__attribute__((address_space(3))) unsigned short*)&Vs[cur][0];
    #pragma unroll
    for (int ks=0; ks<2; ++ks){
      ushort8 pa = *(const ushort8*)(&Pl[wid][lm*72 + ks*32 + lg*8]);
      unsigned a = vsb + ks*4096 + lg*1024 + lm*8;
      u32x2 lo0,hi0,lo1,hi1,lo2,hi2,lo3,hi3;
      asm volatile(
        "ds_read_b64_tr_b16 %0, %8 offset:0\n\t"
        "ds_read_b64_tr_b16 %1, %8 offset:512\n\t"
        "ds_read_b64_tr_b16 %2, %8 offset:128\n\t"
        "ds_read_b64_tr_b16 %3, %8 offset:640\n\t"
        "ds_read_b64_tr_b16 %4, %8 offset:256\n\t"
        "ds_read_b64_tr_b16 %5, %8 offset:768\n\t"
        "ds_read_b64_tr_b16 %6, %8 offset:384\n\t"
        "ds_read_b64_tr_b16 %7, %8 offset:896"
        : "=&v"(lo0),"=&v"(hi0),"=&v"(lo1),"=&v"(hi1),"=&v"(lo2),"=&v"(hi2),"=&v"(lo3),"=&v"(hi3)
        : "v"(a));
      asm volatile("s_waitcnt lgkmcnt(0)" ::: "memory");
      __builtin_amdgcn_sched_barrier(0);
      o[0] = mfma16(pa, mk8(lo0,hi0), o[0]);
      o[1] = mfma16(pa, mk8(lo1,hi1), o[1]);
      o[2] = mfma16(pa, mk8(lo2,hi2), o[2]);
      o[3] = mfma16(pa, mk8(lo3,hi3), o[3]);
    }
    asm volatile("" ::: "memory");
    __builtin_amdgcn_s_barrier();
  }

  // ---- epilogue: row-sum reduce once, normalize, leaky_relu, store ----
  #pragma unroll
  for (int r=0;r<4;r++){
    float s = lp[r];
    #pragma unroll
    for (int x=1;x<16;x<<=1) s += __shfl_xor(s, x, 16);
    lp[r] = 1.0f / fmaxf(s, 1e-30f);
  }
  #pragma unroll
  for (int dn=0;dn<4;dn++)
    #pragma unroll
    for (int r=0;r<4;r++){
      int q = q0 + lg*4 + r;
      float v = o[dn][r] * lp[r];
      v = (v >= 0.f) ? v : 0.01f*v;   // leaky_relu fused
      att[(size_t)(b*N_+q)*DIM_ + h*64 + dn*16 + lm] = f2bf(v);
    }
}

// ---------------- final output dot ----------------
__global__ __launch_bounds__(256) void out_kernel(const float* __restrict__ hf,
    const float* __restrict__ ow, const float* __restrict__ ob, float* __restrict__ out){
  int lane = threadIdx.x & 63;
  int row = blockIdx.x*4 + (threadIdx.x>>6);
  const float* x = hf + (size_t)row*FDIM_;
  float s = 0.f;
  for (int j=lane;j<FDIM_;j+=64) s += x[j]*ow[j];
  #pragma unroll
  for (int off=1; off<64; off<<=1) s += __shfl_xor(s, off, 64);
  if (lane==0) out[row] = s + ob[0];
}

extern "C" void kernel_launch(void* const* d_in, const int* in_sizes, int n_in,
                              void* d_out, int out_size, void* d_ws, size_t ws_size,
                              hipStream_t stream)
{
  const float* x_feats = (const float*)d_in[0];
  const int*   x_toks  = (const int*)d_in[1];
  const float* mask    = (const float*)d_in[2];
  const float* emb0    = (const float*)d_in[3];
  const float* emb1    = (const float*)d_in[4];
  const float* feat_w  = (const float*)d_in[5];
  const float* feat_b  = (const float*)d_in[6];
  const float* qkv_w   = (const float*)d_in[7];
  const float* qkv_b   = (const float*)d_in[8];
  const float* o_w     = (const float*)d_in[9];
  const float* ln1_g   = (const float*)d_in[10];
  const float* ln1_b   = (const float*)d_in[11];
  const float* ln2_g   = (const float*)d_in[12];
  const float* ln2_b   = (const float*)d_in[13];
  const float* p1_w    = (const float*)d_in[14];
  const float* p1_b    = (const float*)d_in[15];
  const float* p2_w    = (const float*)d_in[16];
  const float* p2_b    = (const float*)d_in[17];
  const float* fn_g    = (const float*)d_in[18];
  const float* fn_b    = (const float*)d_in[19];
  const float* lin1_w  = (const float*)d_in[20];
  const float* lin1_b  = (const float*)d_in[21];
  const float* rb1_w   = (const float*)d_in[22];
  const float* rb1_b   = (const float*)d_in[23];
  const float* rb2_w   = (const float*)d_in[24];
  const float* rb2_b   = (const float*)d_in[25];
  const float* out_w   = (const float*)d_in[26];
  const float* out_b   = (const float*)d_in[27];
  float* out = (float*)d_out;

  char* w = (char*)d_ws;
  auto alloc = [&](size_t bytes)->void*{ void* p = (void*)w; w += (bytes + 255) & ~(size_t)255; return p; };

  float* Z              = (float*)alloc((size_t)ROWS_*DIM_*4);
  unsigned short* Zn    = (unsigned short*)alloc((size_t)ROWS_*DIM_*2);
  unsigned short* qkvB  = (unsigned short*)alloc((size_t)ROWS_*1920*2);
  unsigned short* attB  = (unsigned short*)alloc((size_t)ROWS_*DIM_*2);
  unsigned short* Hb    = (unsigned short*)alloc((size_t)ROWS_*DINNER_*2);
  float* hf             = (float*)alloc((size_t)ROWS_*FDIM_*4);
  unsigned short* hb1   = (unsigned short*)alloc((size_t)ROWS_*FDIMP_*2);
  unsigned short* hb2   = (unsigned short*)alloc((size_t)ROWS_*FDIMP_*2);
  unsigned short* qkvw  = (unsigned short*)alloc((size_t)L_*1920*DIM_*2);
  unsigned short* oww   = (unsigned short*)alloc((size_t)L_*DIM_*DIM_*2);
  unsigned short* p1w   = (unsigned short*)alloc((size_t)L_*DINNER_*DIM_*2);
  unsigned short* p2w   = (unsigned short*)alloc((size_t)L_*DIM_*DINNER_*2);
  unsigned short* l1w   = (unsigned short*)alloc((size_t)FDIM_*DIM_*2);
  unsigned short* r1w   = (unsigned short*)alloc((size_t)FDIM_*FDIMP_*2);
  unsigned short* r2w   = (unsigned short*)alloc((size_t)FDIM_*FDIMP_*2);

  conv_kernel<<<2048,256,0,stream>>>(qkv_w, qkvw, L_*1920*DIM_);
  conv_kernel<<<1024,256,0,stream>>>(o_w,   oww,  L_*DIM_*DIM_);
  conv_kernel<<<2048,256,0,stream>>>(p1_w,  p1w,  L_*DINNER_*DIM_);
  conv_kernel<<<2048,256,0,stream>>>(p2_w,  p2w,  L_*DIM_*DINNER_);
  conv_kernel<<<256,256,0,stream>>>(lin1_w, l1w,  FDIM_*DIM_);
  convpad_kernel<<<128,256,0,stream>>>(rb1_w, r1w, FDIM_, FDIM_, FDIMP_);
  convpad_kernel<<<128,256,0,stream>>>(rb2_w, r2w, FDIM_, FDIM_, FDIMP_);
  hipMemsetAsync(hb1, 0, (size_t)ROWS_*FDIMP_*2, stream);
  hipMemsetAsync(hb2, 0, (size_t)ROWS_*FDIMP_*2, stream);

  embed_kernel<<<ROWS_,256,0,stream>>>(x_feats, x_toks, emb0, emb1, feat_w, feat_b, Z);

  for (int l=0; l<L_; l++){
    ln_kernel<<<ROWS_/4,256,0,stream>>>(Z, ln1_g + l*DIM_, ln1_b + l*DIM_, Zn);
    gemm_kernel<true,false,false,false,true><<<dim3(15,32),256,0,stream>>>(
        Zn, DIM_, qkvw + (size_t)l*1920*DIM_, DIM_, qkv_b + l*1920,
        nullptr, 0, nullptr, 0, qkvB, 1920, 1920, DIM_);
    attn_kernel<<<dim3(N_/64, B_*NH_),256,0,stream>>>(qkvB, mask, attB);
    gemm_kernel<false,false,true,true,false><<<dim3(5,32),256,0,stream>>>(
        attB, DIM_, oww + (size_t)l*DIM_*DIM_, DIM_, nullptr,
        Z, DIM_, Z, DIM_, nullptr, 0, DIM_, DIM_);
    ln_kernel<<<ROWS_/4,256,0,stream>>>(Z, ln2_g + l*DIM_, ln2_b + l*DIM_, Zn);
    gemm_kernel<true,true,false,false,true><<<dim3(20,32),256,0,stream>>>(
        Zn, DIM_, p1w + (size_t)l*DINNER_*DIM_, DIM_, p1_b + l*DINNER_,
        nullptr, 0, nullptr, 0, Hb, DINNER_, DINNER_, DIM_);
    gemm_kernel<true,false,true,true,false><<<dim3(5,32),256,0,stream>>>(
        Hb, DINNER_, p2w + (size_t)l*DIM_*DINNER_, DINNER_, p2_b + l*DIM_,
        Z, DIM_, Z, DIM_, nullptr, 0, DIM_, DINNER_);
  }

  ln_kernel<<<ROWS_/4,256,0,stream>>>(Z, fn_g, fn_b, Zn);
  gemm_kernel<true,false,false,true,true><<<dim3(3,32),256,0,stream>>>(
      Zn, DIM_, l1w, DIM_, lin1_b, nullptr, 0, hf, FDIM_, hb1, FDIMP_, FDIM_, DIM_);
  gemm_kernel<true,true,false,false,true><<<dim3(3,32),256,0,stream>>>(
      hb1, FDIMP_, r1w, FDIMP_, rb1_b, nullptr, 0, nullptr, 0, hb2, FDIMP_, FDIM_, FDIMP_);
  gemm_kernel<true,false,true,true,false><<<dim3(3,32),256,0,stream>>>(
      hb2, FDIMP_, r2w, FDIMP_, rb2_b, hf, FDIM_, hf, FDIM_, nullptr, 0, FDIM_, FDIMP_);
  out_kernel<<<ROWS_/4,256,0,stream>>>(hf, out_w, out_b, out);
}

// Round 4
// 872.733 us; speedup vs baseline: 1.6946x; 1.0688x over previous
//
#include <hip/hip_runtime.h>

#define B_ 2
#define N_ 2048
#define DIM_ 640
#define NH_ 10
#define DH_ 64
#define DINNER_ 2560
#define L_ 4
#define FDIM_ 280
#define FDIMP_ 288
#define FEATD_ 576
#define NFEAT_ 19
#define ROWS_ (B_*N_)   /* 4096 */

typedef __attribute__((ext_vector_type(8))) unsigned short ushort8;
typedef __attribute__((ext_vector_type(8))) __bf16 bf16x8;
typedef __attribute__((ext_vector_type(4))) float f32x4;
typedef __attribute__((ext_vector_type(2))) unsigned int u32x2;

static __device__ __forceinline__ unsigned short f2bf(float f){
  unsigned int u = __builtin_bit_cast(unsigned int, f);
  u += 0x7fffu + ((u >> 16) & 1u);
  return (unsigned short)(u >> 16);
}

static __device__ __forceinline__ f32x4 mfma16(ushort8 a, ushort8 b, f32x4 c){
  return __builtin_amdgcn_mfma_f32_16x16x32_bf16(
      __builtin_bit_cast(bf16x8, a), __builtin_bit_cast(bf16x8, b), c, 0, 0, 0);
}

static __device__ __forceinline__ ushort8 mk8(u32x2 lo, u32x2 hi){
  union { unsigned int u[4]; ushort8 s; } u_;
  u_.u[0]=lo[0]; u_.u[1]=lo[1]; u_.u[2]=hi[0]; u_.u[3]=hi[1];
  return u_.s;
}

#define GLD(src,dst) __builtin_amdgcn_global_load_lds((const __attribute__((address_space(1))) void*)(src), (__attribute__((address_space(3))) void*)(dst), 16, 0, 0)

// ---------------- weight conversion ----------------
__global__ __launch_bounds__(256) void conv_kernel(const float* __restrict__ src,
    unsigned short* __restrict__ dst, int n){
  int i = blockIdx.x*256 + threadIdx.x;
  int stride = gridDim.x*256;
  for (; i<n; i+=stride) dst[i] = f2bf(src[i]);
}

__global__ __launch_bounds__(256) void convpad_kernel(const float* __restrict__ src,
    unsigned short* __restrict__ dst, int rows, int cols, int ld){
  int n = rows*ld;
  int i = blockIdx.x*256 + threadIdx.x;
  int stride = gridDim.x*256;
  for (; i<n; i+=stride){
    int r = i/ld, c = i%ld;
    dst[i] = (c<cols) ? f2bf(src[r*cols+c]) : (unsigned short)0;
  }
}

// ---------------- embedding ----------------
__global__ __launch_bounds__(256) void embed_kernel(const float* __restrict__ xf,
    const int* __restrict__ xt, const float* __restrict__ e0, const float* __restrict__ e1,
    const float* __restrict__ fw, const float* __restrict__ fb, float* __restrict__ Z){
  int row = blockIdx.x;
  __shared__ float f[NFEAT_];
  int t = threadIdx.x;
  if (t < NFEAT_) f[t] = xf[row*NFEAT_ + t];
  __syncthreads();
  if (t < 32) {
    int tok0 = xt[row*2];
    Z[(size_t)row*DIM_ + t] = e0[tok0*32 + t];
  } else if (t < 64) {
    int tok1 = xt[row*2+1];
    Z[(size_t)row*DIM_ + t] = e1[tok1*32 + (t-32)];
  }
  for (int fo = t; fo < FEATD_; fo += 256){
    float acc = fb[fo];
    #pragma unroll
    for (int k=0;k<NFEAT_;k++) acc += f[k]*fw[fo*NFEAT_+k];
    Z[(size_t)row*DIM_ + 64 + fo] = acc;
  }
}

// ---------------- layernorm (fp32 in -> bf16 out) ----------------
__global__ __launch_bounds__(256) void ln_kernel(const float* __restrict__ X,
    const float* __restrict__ g, const float* __restrict__ bb,
    unsigned short* __restrict__ out){
  int lane = threadIdx.x & 63;
  int row = blockIdx.x*4 + (threadIdx.x >> 6);
  const float* x = X + (size_t)row*DIM_;
  float v[10]; float s=0.f, sq=0.f;
  #pragma unroll
  for (int j=0;j<10;j++){ float t = x[lane + j*64]; v[j]=t; s+=t; sq+=t*t; }
  #pragma unroll
  for (int off=1; off<64; off<<=1){ s += __shfl_xor(s, off, 64); sq += __shfl_xor(sq, off, 64); }
  float mean = s*(1.f/DIM_);
  float var = sq*(1.f/DIM_) - mean*mean;
  float rstd = rsqrtf(var + 1e-5f);
  unsigned short* o = out + (size_t)row*DIM_;
  #pragma unroll
  for (int j=0;j<10;j++){ int c = lane + j*64; o[c] = f2bf((v[j]-mean)*rstd*g[c] + bb[c]); }
}

// ---------------- GEMM: C = A(MxK) * Bw(NxK)^T, 128x128 tile, 2-phase dbuf ----------------
template<bool BIAS, bool RELU, bool RES, bool OUTF, bool OUTB>
__global__ __launch_bounds__(256) void gemm_kernel(
    const unsigned short* __restrict__ A, int lda,
    const unsigned short* __restrict__ Bw, int ldb,
    const float* __restrict__ bias,
    const float* __restrict__ Res, int ldres,
    float* __restrict__ Cf, int ldcf,
    unsigned short* __restrict__ Cb, int ldcb,
    int Ncols, int K)
{
  __shared__ __align__(16) unsigned short As[2][128*32];
  __shared__ __align__(16) unsigned short Bs[2][128*32];
  int t = threadIdx.x;
  int wid = t >> 6, lane = t & 63;
  int wr = wid >> 1, wc = wid & 1;
  int lg = lane >> 4, lm = lane & 15;
  int row0 = blockIdx.y * 128;
  int col0 = blockIdx.x * 128;

  // staging addresses (each thread: 2 A-chunks + 2 B-chunks of 16B per k-step)
  int c0 = wid*128 + lane, c1 = c0 + 64;
  int ar0 = c0 >> 2, aq0 = c0 & 3;
  int ar1 = c1 >> 2, aq1 = c1 & 3;
  const unsigned short* a0 = A + (size_t)(row0+ar0)*lda + aq0*8;
  const unsigned short* a1 = A + (size_t)(row0+ar1)*lda + aq1*8;
  int br0 = col0+ar0; if (br0 >= Ncols) br0 = Ncols-1;
  int br1 = col0+ar1; if (br1 >= Ncols) br1 = Ncols-1;
  const unsigned short* b0 = Bw + (size_t)br0*ldb + aq0*8;
  const unsigned short* b1 = Bw + (size_t)br1*ldb + aq1*8;

  f32x4 acc[4][4];
  #pragma unroll
  for (int m=0;m<4;m++)
    #pragma unroll
    for (int n=0;n<4;n++) acc[m][n] = f32x4{0.f,0.f,0.f,0.f};

  int nk = K >> 5;
  // prologue: stage tile 0
  GLD(a0, &As[0][c0*8]); GLD(b0, &Bs[0][c0*8]);
  GLD(a1, &As[0][c1*8]); GLD(b1, &Bs[0][c1*8]);

  for (int tk=0; tk<nk; ++tk){
    int cur = tk & 1;
    if (tk+1 < nk){
      int kt = (tk+1) << 5;
      GLD(a0+kt, &As[cur^1][c0*8]); GLD(b0+kt, &Bs[cur^1][c0*8]);
      GLD(a1+kt, &As[cur^1][c1*8]); GLD(b1+kt, &Bs[cur^1][c1*8]);
      asm volatile("s_waitcnt vmcnt(4)" ::: "memory");
    } else {
      asm volatile("s_waitcnt vmcnt(0)" ::: "memory");
    }
    __builtin_amdgcn_s_barrier();
    asm volatile("" ::: "memory");
    ushort8 af[4], bfr[4];
    #pragma unroll
    for (int m=0;m<4;m++) af[m] = *(const ushort8*)(&As[cur][(wr*64 + m*16 + lm)*32 + lg*8]);
    #pragma unroll
    for (int n=0;n<4;n++) bfr[n] = *(const ushort8*)(&Bs[cur][(wc*64 + n*16 + lm)*32 + lg*8]);
    #pragma unroll
    for (int m=0;m<4;m++)
      #pragma unroll
      for (int n=0;n<4;n++)
        acc[m][n] = mfma16(af[m], bfr[n], acc[m][n]);
    asm volatile("" ::: "memory");
    __builtin_amdgcn_s_barrier();
  }

  #pragma unroll
  for (int m=0;m<4;m++){
    int rbase = row0 + wr*64 + m*16 + lg*4;
    #pragma unroll
    for (int n=0;n<4;n++){
      int cc = col0 + wc*64 + n*16 + lm;
      if (cc < Ncols){
        float bv = 0.f;
        if (BIAS) bv = bias[cc];
        #pragma unroll
        for (int rr=0;rr<4;rr++){
          float v = acc[m][n][rr] + bv;
          if (RELU) v = fmaxf(v, 0.f);
          if (RES) v += Res[(size_t)(rbase+rr)*ldres + cc];
          if (OUTF) Cf[(size_t)(rbase+rr)*ldcf + cc] = v;
          if (OUTB) Cb[(size_t)(rbase+rr)*ldcb + cc] = f2bf(v);
        }
      }
    }
  }
}

// ---------------- flash attention, KVBLK=64, double-buffered, swizzled K, subtiled V + tr reads
// qkv bf16 [row][h*192 + {V:0,Q:64,K:128}+d]
__global__ __launch_bounds__(256) void attn_kernel(const unsigned short* __restrict__ qkv,
    const float* __restrict__ mask, unsigned short* __restrict__ att){
  int bh = blockIdx.y; int b = bh/NH_, h = bh%NH_;
  int t = threadIdx.x; int wid = t>>6, lane = t&63, lg = lane>>4, lm = lane&15;
  int q0 = blockIdx.x*64 + wid*16;

  __shared__ __align__(128) unsigned short Ks[2][4096];
  __shared__ __align__(128) unsigned short Vs[2][4096];
  __shared__ __align__(16) unsigned short Pl[4][16*72];
  __shared__ __align__(16) float maskL[N_];

  const size_t base = (size_t)b*N_*1920 + (size_t)h*192;

  // per-thread staging constants (chunk = 16B)
  int c0 = t, c1 = t+256;
  int kk0 = c0>>3, kc0 = (c0&7)^(kk0&7);
  int kk1 = c1>>3, kc1 = (c1&7)^(kk1&7);
  const unsigned short* kS0 = qkv + base + 128 + (size_t)kk0*1920 + kc0*8;
  const unsigned short* kS1 = qkv + base + 128 + (size_t)kk1*1920 + kc1*8;
  // V subtiled [k>>2][d>>4][k&3][d&15]: chunk c -> k = ((c>>5)<<2)|((c>>1)&3), d8 = (((c>>3)&3)<<1)|(c&1)
  int vk0 = ((c0>>5)<<2)|((c0>>1)&3), vd0 = (((c0>>3)&3)<<1)|(c0&1);
  int vk1 = ((c1>>5)<<2)|((c1>>1)&3), vd1 = (((c1>>3)&3)<<1)|(c1&1);
  const unsigned short* vS0 = qkv + base + (size_t)vk0*1920 + vd0*8;
  const unsigned short* vS1 = qkv + base + (size_t)vk1*1920 + vd1*8;

  // Q fragments + query-row mask (issued before staging -> older in vmcnt order)
  ushort8 qf[2];
  #pragma unroll
  for (int ss=0; ss<2; ss++)
    qf[ss] = *(const ushort8*)(qkv + base + (size_t)(q0+lm)*1920 + 64 + ss*32 + lg*8);
  float mq[4];
  #pragma unroll
  for (int r=0;r<4;r++) mq[r] = mask[b*N_ + q0 + lg*4 + r];

  // prologue staging: mask row + tile 0
  GLD(mask + b*N_ + c0*4, &maskL[c0*4]);
  GLD(mask + b*N_ + c1*4, &maskL[c1*4]);
  GLD(kS0, &Ks[0][c0*8]); GLD(kS1, &Ks[0][c1*8]);
  GLD(vS0, &Vs[0][c0*8]); GLD(vS1, &Vs[0][c1*8]);

  float lp[4] = {0.f,0.f,0.f,0.f};
  f32x4 o[4];
  #pragma unroll
  for (int dn=0;dn<4;dn++) o[dn] = f32x4{0.f,0.f,0.f,0.f};

  for (int it=0; it<N_/64; ++it){
    int cur = it & 1;
    if (it < N_/64 - 1){
      const size_t adv = (size_t)(it+1)*64*1920;
      GLD(kS0+adv, &Ks[1-cur][c0*8]); GLD(kS1+adv, &Ks[1-cur][c1*8]);
      GLD(vS0+adv, &Vs[1-cur][c0*8]); GLD(vS1+adv, &Vs[1-cur][c1*8]);
      asm volatile("s_waitcnt vmcnt(4)" ::: "memory");
    } else {
      asm volatile("s_waitcnt vmcnt(0)" ::: "memory");
    }
    __builtin_amdgcn_s_barrier();
    asm volatile("" ::: "memory");

    // ---- QK^T (swizzled K reads) ----
    const unsigned short* Kc = &Ks[cur][0];
    f32x4 sf[4];
    float mk[4];
    #pragma unroll
    for (int c=0;c<4;c++){
      mk[c] = maskL[it*64 + c*16 + lm];
      int krow = c*16 + lm;
      f32x4 s = f32x4{0.f,0.f,0.f,0.f};
      #pragma unroll
      for (int ss=0;ss<2;ss++){
        ushort8 kf = *(const ushort8*)(Kc + (krow*8 + ((ss*4+lg)^(krow&7)))*8);
        s = mfma16(qf[ss], kf, s);
      }
      sf[c] = s;
    }

    // ---- fixed-max softmax numerators (scale-invariant; masked -> exact 0) ----
    float pm[4][4];
    #pragma unroll
    for (int c=0;c<4;c++){
      #pragma unroll
      for (int r=0;r<4;r++){
        float x = fmaf(sf[c][r], 0.125f, -12.0f);
        x = (mq[r]*mk[c] > 0.f) ? x : -1e30f;
        pm[c][r] = __expf(x);
      }
    }
    #pragma unroll
    for (int r=0;r<4;r++) lp[r] += (pm[0][r]+pm[1][r]) + (pm[2][r]+pm[3][r]);
    #pragma unroll
    for (int c=0;c<4;c++)
      #pragma unroll
      for (int r=0;r<4;r++)
        Pl[wid][(lg*4+r)*72 + c*16 + lm] = f2bf(pm[c][r]);

    // ---- P·V via hardware transpose reads on subtiled V ----
    // tr_b16 semantics: elem j = tile128B(addr & ~127)[row j][col (addr&127)>>3]
    unsigned vsb = (unsigned)(size_t)(__attribute__((address_space(3))) unsigned short*)&Vs[cur][0];
    #pragma unroll
    for (int ks=0; ks<2; ++ks){
      ushort8 pa = *(const ushort8*)(&Pl[wid][lm*72 + ks*32 + lg*8]);
      unsigned a = vsb + ks*4096 + lg*1024 + lm*8;
      u32x2 lo0,hi0,lo1,hi1,lo2,hi2,lo3,hi3;
      asm volatile(
        "ds_read_b64_tr_b16 %0, %8 offset:0\n\t"
        "ds_read_b64_tr_b16 %1, %8 offset:512\n\t"
        "ds_read_b64_tr_b16 %2, %8 offset:128\n\t"
        "ds_read_b64_tr_b16 %3, %8 offset:640\n\t"
        "ds_read_b64_tr_b16 %4, %8 offset:256\n\t"
        "ds_read_b64_tr_b16 %5, %8 offset:768\n\t"
        "ds_read_b64_tr_b16 %6, %8 offset:384\n\t"
        "ds_read_b64_tr_b16 %7, %8 offset:896"
        : "=&v"(lo0),"=&v"(hi0),"=&v"(lo1),"=&v"(hi1),"=&v"(lo2),"=&v"(hi2),"=&v"(lo3),"=&v"(hi3)
        : "v"(a));
      asm volatile("s_waitcnt lgkmcnt(0)" ::: "memory");
      __builtin_amdgcn_sched_barrier(0);
      o[0] = mfma16(pa, mk8(lo0,hi0), o[0]);
      o[1] = mfma16(pa, mk8(lo1,hi1), o[1]);
      o[2] = mfma16(pa, mk8(lo2,hi2), o[2]);
      o[3] = mfma16(pa, mk8(lo3,hi3), o[3]);
    }
    asm volatile("" ::: "memory");
    __builtin_amdgcn_s_barrier();
  }

  // ---- epilogue: row-sum reduce once, normalize, leaky_relu, store ----
  #pragma unroll
  for (int r=0;r<4;r++){
    float s = lp[r];
    #pragma unroll
    for (int x=1;x<16;x<<=1) s += __shfl_xor(s, x, 16);
    lp[r] = 1.0f / fmaxf(s, 1e-30f);
  }
  #pragma unroll
  for (int dn=0;dn<4;dn++)
    #pragma unroll
    for (int r=0;r<4;r++){
      int q = q0 + lg*4 + r;
      float v = o[dn][r] * lp[r];
      v = (v >= 0.f) ? v : 0.01f*v;   // leaky_relu fused
      att[(size_t)(b*N_+q)*DIM_ + h*64 + dn*16 + lm] = f2bf(v);
    }
}

// ---------------- final output dot ----------------
__global__ __launch_bounds__(256) void out_kernel(const float* __restrict__ hf,
    const float* __restrict__ ow, const float* __restrict__ ob, float* __restrict__ out){
  int lane = threadIdx.x & 63;
  int row = blockIdx.x*4 + (threadIdx.x>>6);
  const float* x = hf + (size_t)row*FDIM_;
  float s = 0.f;
  for (int j=lane;j<FDIM_;j+=64) s += x[j]*ow[j];
  #pragma unroll
  for (int off=1; off<64; off<<=1) s += __shfl_xor(s, off, 64);
  if (lane==0) out[row] = s + ob[0];
}

extern "C" void kernel_launch(void* const* d_in, const int* in_sizes, int n_in,
                              void* d_out, int out_size, void* d_ws, size_t ws_size,
                              hipStream_t stream)
{
  const float* x_feats = (const float*)d_in[0];
  const int*   x_toks  = (const int*)d_in[1];
  const float* mask    = (const float*)d_in[2];
  const float* emb0    = (const float*)d_in[3];
  const float* emb1    = (const float*)d_in[4];
  const float* feat_w  = (const float*)d_in[5];
  const float* feat_b  = (const float*)d_in[6];
  const float* qkv_w   = (const float*)d_in[7];
  const float* qkv_b   = (const float*)d_in[8];
  const float* o_w     = (const float*)d_in[9];
  const float* ln1_g   = (const float*)d_in[10];
  const float* ln1_b   = (const float*)d_in[11];
  const float* ln2_g   = (const float*)d_in[12];
  const float* ln2_b   = (const float*)d_in[13];
  const float* p1_w    = (const float*)d_in[14];
  const float* p1_b    = (const float*)d_in[15];
  const float* p2_w    = (const float*)d_in[16];
  const float* p2_b    = (const float*)d_in[17];
  const float* fn_g    = (const float*)d_in[18];
  const float* fn_b    = (const float*)d_in[19];
  const float* lin1_w  = (const float*)d_in[20];
  const float* lin1_b  = (const float*)d_in[21];
  const float* rb1_w   = (const float*)d_in[22];
  const float* rb1_b   = (const float*)d_in[23];
  const float* rb2_w   = (const float*)d_in[24];
  const float* rb2_b   = (const float*)d_in[25];
  const float* out_w   = (const float*)d_in[26];
  const float* out_b   = (const float*)d_in[27];
  float* out = (float*)d_out;

  char* w = (char*)d_ws;
  auto alloc = [&](size_t bytes)->void*{ void* p = (void*)w; w += (bytes + 255) & ~(size_t)255; return p; };

  float* Z              = (float*)alloc((size_t)ROWS_*DIM_*4);
  unsigned short* Zn    = (unsigned short*)alloc((size_t)ROWS_*DIM_*2);
  unsigned short* qkvB  = (unsigned short*)alloc((size_t)ROWS_*1920*2);
  unsigned short* attB  = (unsigned short*)alloc((size_t)ROWS_*DIM_*2);
  unsigned short* Hb    = (unsigned short*)alloc((size_t)ROWS_*DINNER_*2);
  float* hf             = (float*)alloc((size_t)ROWS_*FDIM_*4);
  unsigned short* hb1   = (unsigned short*)alloc((size_t)ROWS_*FDIMP_*2);
  unsigned short* hb2   = (unsigned short*)alloc((size_t)ROWS_*FDIMP_*2);
  unsigned short* qkvw  = (unsigned short*)alloc((size_t)L_*1920*DIM_*2);
  unsigned short* oww   = (unsigned short*)alloc((size_t)L_*DIM_*DIM_*2);
  unsigned short* p1w   = (unsigned short*)alloc((size_t)L_*DINNER_*DIM_*2);
  unsigned short* p2w   = (unsigned short*)alloc((size_t)L_*DIM_*DINNER_*2);
  unsigned short* l1w   = (unsigned short*)alloc((size_t)FDIM_*DIM_*2);
  unsigned short* r1w   = (unsigned short*)alloc((size_t)FDIM_*FDIMP_*2);
  unsigned short* r2w   = (unsigned short*)alloc((size_t)FDIM_*FDIMP_*2);

  conv_kernel<<<2048,256,0,stream>>>(qkv_w, qkvw, L_*1920*DIM_);
  conv_kernel<<<1024,256,0,stream>>>(o_w,   oww,  L_*DIM_*DIM_);
  conv_kernel<<<2048,256,0,stream>>>(p1_w,  p1w,  L_*DINNER_*DIM_);
  conv_kernel<<<2048,256,0,stream>>>(p2_w,  p2w,  L_*DIM_*DINNER_);
  conv_kernel<<<256,256,0,stream>>>(lin1_w, l1w,  FDIM_*DIM_);
  convpad_kernel<<<128,256,0,stream>>>(rb1_w, r1w, FDIM_, FDIM_, FDIMP_);
  convpad_kernel<<<128,256,0,stream>>>(rb2_w, r2w, FDIM_, FDIM_, FDIMP_);
  hipMemsetAsync(hb1, 0, (size_t)ROWS_*FDIMP_*2, stream);
  hipMemsetAsync(hb2, 0, (size_t)ROWS_*FDIMP_*2, stream);

  embed_kernel<<<ROWS_,256,0,stream>>>(x_feats, x_toks, emb0, emb1, feat_w, feat_b, Z);

  for (int l=0; l<L_; l++){
    ln_kernel<<<ROWS_/4,256,0,stream>>>(Z, ln1_g + l*DIM_, ln1_b + l*DIM_, Zn);
    gemm_kernel<true,false,false,false,true><<<dim3(15,32),256,0,stream>>>(
        Zn, DIM_, qkvw + (size_t)l*1920*DIM_, DIM_, qkv_b + l*1920,
        nullptr, 0, nullptr, 0, qkvB, 1920, 1920, DIM_);
    attn_kernel<<<dim3(N_/64, B_*NH_),256,0,stream>>>(qkvB, mask, attB);
    gemm_kernel<false,false,true,true,false><<<dim3(5,32),256,0,stream>>>(
        attB, DIM_, oww + (size_t)l*DIM_*DIM_, DIM_, nullptr,
        Z, DIM_, Z, DIM_, nullptr, 0, DIM_, DIM_);
    ln_kernel<<<ROWS_/4,256,0,stream>>>(Z, ln2_g + l*DIM_, ln2_b + l*DIM_, Zn);
    gemm_kernel<true,true,false,false,true><<<dim3(20,32),256,0,stream>>>(
        Zn, DIM_, p1w + (size_t)l*DINNER_*DIM_, DIM_, p1_b + l*DINNER_,
        nullptr, 0, nullptr, 0, Hb, DINNER_, DINNER_, DIM_);
    gemm_kernel<true,false,true,true,false><<<dim3(5,32),256,0,stream>>>(
        Hb, DINNER_, p2w + (size_t)l*DIM_*DINNER_, DINNER_, p2_b + l*DIM_,
        Z, DIM_, Z, DIM_, nullptr, 0, DIM_, DINNER_);
  }

  ln_kernel<<<ROWS_/4,256,0,stream>>>(Z, fn_g, fn_b, Zn);
  gemm_kernel<true,false,false,true,true><<<dim3(3,32),256,0,stream>>>(
      Zn, DIM_, l1w, DIM_, lin1_b, nullptr, 0, hf, FDIM_, hb1, FDIMP_, FDIM_, DIM_);
  gemm_kernel<true,true,false,false,true><<<dim3(3,32),256,0,stream>>>(
      hb1, FDIMP_, r1w, FDIMP_, rb1_b, nullptr, 0, nullptr, 0, hb2, FDIMP_, FDIM_, FDIMP_);
  gemm_kernel<true,false,true,true,false><<<dim3(3,32),256,0,stream>>>(
      hb2, FDIMP_, r2w, FDIMP_, rb2_b, hf, FDIM_, hf, FDIM_, nullptr, 0, FDIM_, FDIMP_);
  out_kernel<<<ROWS_/4,256,0,stream>>>(hf, out_w, out_b, out);
}